// Round 1
// baseline (354.568 us; speedup 1.0000x reference)
//
#include <hip/hip_runtime.h>

// RuleGraphConvLayer: out[i] = sel ? ([self_f | comb] @ [w_s; w_n[:81]]) : 0
//   self_f = features[i, 0:81]
//   sel    = idx1 != 0 ? idx1 : (idx0 != 0 ? idx0 : dead)
//   comb   = [nei[0:3], self[3:81]+nei[3:81]] / d_eff^2,  d = |self[:3]-nei[:3]|
constexpr int kNodes  = 262144;
constexpr int NC      = 103;   // feature columns
constexpr int F       = 81;    // used features
constexpr int OC      = 128;   // output channels
constexpr int K2      = 162;   // 81 self + 81 comb
constexpr int KP      = 164;   // padded K (multiple of 4)
constexpr int NPB     = 64;    // nodes per block
constexpr int THREADS = 512;

__global__ __launch_bounds__(THREADS)
void rgc_kernel(const float* __restrict__ feat,
                const float* __restrict__ w_s,
                const float* __restrict__ w_n,
                float* __restrict__ out) {
  __shared__ float w_lds[KP * OC];   // 164*128*4 = 83968 B
  __shared__ float a_lds[NPB * KP];  // 64*164*4  = 41984 B
  __shared__ float s_self[NPB];
  __shared__ float s_comb[NPB];
  __shared__ int   s_sel[NPB];

  const int  tid  = threadIdx.x;
  const long base = (long)blockIdx.x * NPB;

  // ---- Phase 1: combined weights -> LDS (rows 0..80 = w_s, 81..161 = w_n[:81], 162..163 = 0)
  for (int i = tid; i < K2 * OC; i += THREADS) {
    int k = i >> 7;      // /128
    int c = i & 127;
    w_lds[i] = (k < F) ? w_s[k * OC + c] : w_n[(k - F) * OC + c];
  }
  if (tid < 2 * OC) w_lds[K2 * OC + tid] = 0.f;

  // ---- Phase 2a: per-node neighbor select + scales
  if (tid < NPB) {
    const float* row = feat + (base + tid) * NC;
    int i0 = (int)row[F];
    int i1 = (int)row[F + 1];
    int sel; float alive;
    if (i1 != 0)      { sel = i1; alive = 1.f; }
    else if (i0 != 0) { sel = i0; alive = 1.f; }
    else              { sel = 0;  alive = 0.f; }
    const float* nrow = feat + (long)sel * NC;
    float dx = row[0] - nrow[0];
    float dy = row[1] - nrow[1];
    float dz = row[2] - nrow[2];
    float d2 = dx * dx + dy * dy + dz * dz;
    // d = sqrt(d2); d_eff = d>0 ? d : 0.01  =>  1/d_eff^2 = d2>0 ? 1/d2 : 1e4
    float inv = (d2 > 0.f) ? (1.f / d2) : 10000.f;
    s_sel[tid]  = sel;
    s_self[tid] = alive;         // zeroes the whole row for dead nodes
    s_comb[tid] = alive * inv;
  }
  __syncthreads();

  // ---- Phase 2b: build A tile (64 x 162), zero-padded to 164
  for (int i = tid; i < NPB * K2; i += THREADS) {
    int n = i / K2;
    int k = i - n * K2;
    const float* srow = feat + (base + n) * NC;
    float v;
    if (k < F) {
      v = srow[k] * s_self[n];
    } else {
      int kk = k - F;
      float nv = feat[(long)s_sel[n] * NC + kk];
      float sv = (kk < 3) ? 0.f : srow[kk];   // comb[0:3] = nei coords only
      v = (nv + sv) * s_comb[n];
    }
    a_lds[n * KP + k] = v;
  }
  if (tid < NPB * 2) a_lds[(tid >> 1) * KP + K2 + (tid & 1)] = 0.f;
  __syncthreads();

  // ---- Phase 3: GEMM 64x128, K=164. Thread tile: 4 nodes x 4 channels.
  const int cg = tid & 31;         // channel group: cols 4*cg .. 4*cg+3
  const int ng = (tid >> 5) * 4;   // first node of this thread's 4
  const float* ap = a_lds + ng * KP;
  const float* wp = w_lds + cg * 4;

  float4 acc[4];
  #pragma unroll
  for (int n = 0; n < 4; ++n) acc[n] = make_float4(0.f, 0.f, 0.f, 0.f);

  #pragma unroll 2
  for (int k = 0; k < KP; k += 4) {
    float4 wv0 = *(const float4*)(wp + (k + 0) * OC);
    float4 wv1 = *(const float4*)(wp + (k + 1) * OC);
    float4 wv2 = *(const float4*)(wp + (k + 2) * OC);
    float4 wv3 = *(const float4*)(wp + (k + 3) * OC);
    #pragma unroll
    for (int n = 0; n < 4; ++n) {
      float4 av = *(const float4*)(ap + n * KP + k);
      acc[n].x = fmaf(av.x, wv0.x, acc[n].x);
      acc[n].y = fmaf(av.x, wv0.y, acc[n].y);
      acc[n].z = fmaf(av.x, wv0.z, acc[n].z);
      acc[n].w = fmaf(av.x, wv0.w, acc[n].w);
      acc[n].x = fmaf(av.y, wv1.x, acc[n].x);
      acc[n].y = fmaf(av.y, wv1.y, acc[n].y);
      acc[n].z = fmaf(av.y, wv1.z, acc[n].z);
      acc[n].w = fmaf(av.y, wv1.w, acc[n].w);
      acc[n].x = fmaf(av.z, wv2.x, acc[n].x);
      acc[n].y = fmaf(av.z, wv2.y, acc[n].y);
      acc[n].z = fmaf(av.z, wv2.z, acc[n].z);
      acc[n].w = fmaf(av.z, wv2.w, acc[n].w);
      acc[n].x = fmaf(av.w, wv3.x, acc[n].x);
      acc[n].y = fmaf(av.w, wv3.y, acc[n].y);
      acc[n].z = fmaf(av.w, wv3.z, acc[n].z);
      acc[n].w = fmaf(av.w, wv3.w, acc[n].w);
    }
  }

  #pragma unroll
  for (int n = 0; n < 4; ++n) {
    *(float4*)(out + (base + ng + n) * OC + cg * 4) = acc[n];
  }
}

extern "C" void kernel_launch(void* const* d_in, const int* in_sizes, int n_in,
                              void* d_out, int out_size, void* d_ws, size_t ws_size,
                              hipStream_t stream) {
  const float* feat = (const float*)d_in[0];
  const float* w_s  = (const float*)d_in[1];
  const float* w_n  = (const float*)d_in[2];
  float* outp = (float*)d_out;
  dim3 grid(kNodes / NPB);
  rgc_kernel<<<grid, THREADS, 0, stream>>>(feat, w_s, w_n, outp);
}

// Round 2
// 117.410 us; speedup vs baseline: 3.0199x; 3.0199x over previous
//
#include <hip/hip_runtime.h>

// RuleGraphConvLayer via bf16 MFMA, zero-LDS design.
// out[i] = alive ? ([self_f | comb] @ [w_s; w_n[:81]]) : 0
//   sel  = idx1 ? idx1 : (idx0 ? idx0 : dead)
//   comb = [nei[0:3], self[3:81]+nei[3:81]] * (d2>0 ? 1/d2 : 1e4)
constexpr int kNodes = 262144;
constexpr int NC  = 103;   // feature columns
constexpr int F   = 81;    // used features
constexpr int OC  = 128;   // output channels
constexpr int NKS = 6;     // K steps: 6*32 = 192 >= 162 (padded with zeros)

typedef __attribute__((ext_vector_type(8))) short bf16x8;
typedef __attribute__((ext_vector_type(4))) float f32x4;

__device__ inline ushort f2bf(float f) {
  uint u = __float_as_uint(f);
  return (ushort)((u + 0x7fffu + ((u >> 16) & 1u)) >> 16);  // RNE
}

// Weight table in fragment order: wf[ks][ct][lane] = 8 bf16 (16B), so a wave's
// B-fragment load is one fully-coalesced dwordx4 per lane.
// B[k][c]: k = ks*32 + (lane>>4)*8 + i, c = ct*16 + (lane&15).
__global__ __launch_bounds__(256)
void prep_w(const float* __restrict__ w_s, const float* __restrict__ w_n,
            ushort* __restrict__ wf) {
  int t = blockIdx.x * 256 + threadIdx.x;
  if (t >= NKS * 8 * 64) return;
  int l  = t & 63;
  int ct = (t >> 6) & 7;
  int ks = t >> 9;
  int c  = ct * 16 + (l & 15);
  int kb = ks * 32 + ((l >> 4) << 3);
  union { ushort u[8]; int4 v; } o;
  #pragma unroll
  for (int i = 0; i < 8; ++i) {
    int k = kb + i;
    float f = 0.f;
    if (k < F)          f = w_s[k * OC + c];
    else if (k < 2 * F) f = w_n[(k - F) * OC + c];
    o.u[i] = f2bf(f);
  }
  ((int4*)wf)[t] = o.v;
}

__global__ __launch_bounds__(256)
void rgc_mfma(const float* __restrict__ feat, const ushort* __restrict__ wf,
              float* __restrict__ out) {
  const int tid = threadIdx.x;
  const int l   = tid & 63;
  const int gw  = (blockIdx.x * 256 + tid) >> 6;  // global wave id: 16 nodes
  const int lrow = l & 15;                        // A-frag row within tile
  const int lk   = (l >> 4) << 3;                 // A-frag k sub-offset

  const long node = (long)gw * 16 + lrow;
  const float* srow = feat + node * NC;

  // Per-node preamble (redundant across the 4 lanes sharing a node; L1-hit).
  int i0 = (int)srow[F];
  int i1 = (int)srow[F + 1];
  int sel = (i1 != 0) ? i1 : i0;
  float alive = (i1 != 0 || i0 != 0) ? 1.f : 0.f;
  const float* nrow = feat + (long)sel * NC;
  float dx = srow[0] - nrow[0];
  float dy = srow[1] - nrow[1];
  float dz = srow[2] - nrow[2];
  float d2 = dx * dx + dy * dy + dz * dz;
  float cs = alive * ((d2 > 0.f) ? (1.f / d2) : 10000.f);

  const bf16x8* wfv = (const bf16x8*)wf;

  f32x4 acc[8];
  #pragma unroll
  for (int i = 0; i < 8; ++i) acc[i] = (f32x4)(0.f);

  #pragma unroll
  for (int ks = 0; ks < NKS; ++ks) {
    const int kb = ks * 32 + lk;
    // Build this lane's A fragment: A[lrow][kb .. kb+7] in bf16.
    bf16x8 af;
    #pragma unroll
    for (int i = 0; i < 8; ++i) {
      int k = kb + i;
      float v;
      if (k < F) {
        v = srow[k] * alive;                    // self part (zeroed if dead)
      } else if (k < 2 * F) {
        int kk = k - F;
        float nv = nrow[kk];
        float sv = (kk < 3) ? 0.f : srow[kk];   // comb[0:3] = nei coords only
        v = (nv + sv) * cs;
      } else {
        v = 0.f;                                // K padding 162..191
      }
      af[i] = (short)f2bf(v);
    }
    // 8 column tiles of 16; B frags coalesced from the pre-swizzled table.
    #pragma unroll
    for (int ct = 0; ct < 8; ++ct) {
      bf16x8 bfr = wfv[(ks * 8 + ct) * 64 + l];
      acc[ct] = __builtin_amdgcn_mfma_f32_16x16x32_bf16(af, bfr, acc[ct], 0, 0, 0);
    }
  }

  // C/D layout: col = lane&15, row = (lane>>4)*4 + reg  [learn_hip m89/m91]
  const long orow = (long)gw * 16 + ((l >> 4) << 2);
  const int  col  = l & 15;
  #pragma unroll
  for (int ct = 0; ct < 8; ++ct) {
    #pragma unroll
    for (int r = 0; r < 4; ++r) {
      out[(orow + r) * OC + ct * 16 + col] = acc[ct][r];
    }
  }
}

extern "C" void kernel_launch(void* const* d_in, const int* in_sizes, int n_in,
                              void* d_out, int out_size, void* d_ws, size_t ws_size,
                              hipStream_t stream) {
  const float* feat = (const float*)d_in[0];
  const float* w_s  = (const float*)d_in[1];
  const float* w_n  = (const float*)d_in[2];
  float* outp = (float*)d_out;
  ushort* wf = (ushort*)d_ws;  // 6*8*64*8 bf16 = 49152 bytes

  prep_w<<<dim3((NKS * 8 * 64 + 255) / 256), 256, 0, stream>>>(w_s, w_n, wf);

  const int waves = kNodes / 16;              // 16384 waves, 16 nodes each
  rgc_mfma<<<dim3(waves / 4), 256, 0, stream>>>(feat, wf, outp);
}